// Round 6
// baseline (23492.113 us; speedup 1.0000x reference)
//
#include <hip/hip_runtime.h>
#include <hip/hip_bf16.h>

#if __has_builtin(__builtin_amdgcn_exp2f)
#define EXP2F(x) __builtin_amdgcn_exp2f(x)
#else
#define EXP2F(x) exp2f(x)
#endif
#if __has_builtin(__builtin_amdgcn_rcpf)
#define RCPF(x) __builtin_amdgcn_rcpf(x)
#else
#define RCPF(x) (1.0f/(x))
#endif

typedef _Float16 h2f16 __attribute__((ext_vector_type(2)));

namespace {
constexpr int   kT   = 127;
constexpr int   kE   = 128;
constexpr int   kB   = 4096;
constexpr int   kNWG = 512;
constexpr int   kBPW = kB / kNWG;          // 8 batches per block, sequential
constexpr float kLog2e = 1.4426950408889634f;
constexpr float kK2    = 2.8853900817779268f;   // 2*log2(e)
// LDS: u2u 8128u + hc2 128u + f32[10*128 + 256 + 130]
constexpr int   kSmemBytes = (8128 + 128) * 4 + (10 * 128 + 256 + 130) * 4;

__device__ __forceinline__ unsigned int packf16(float a, float b) {
  h2f16 h = { (_Float16)a, (_Float16)b };
  return __builtin_bit_cast(unsigned int, h);
}
__device__ __forceinline__ float lo16f(unsigned int u) {
  h2f16 h = __builtin_bit_cast(h2f16, u); return (float)h.x;
}
__device__ __forceinline__ float hi16f(unsigned int u) {
  h2f16 h = __builtin_bit_cast(h2f16, u); return (float)h.y;
}

#if __has_builtin(__builtin_amdgcn_fdot2)
__device__ __forceinline__ float fdot2f(unsigned int a, unsigned int b, float c) {
  return __builtin_amdgcn_fdot2(__builtin_bit_cast(h2f16, a),
                                __builtin_bit_cast(h2f16, b), c, false);
}
#else
__device__ __forceinline__ float fdot2f(unsigned int a, unsigned int b, float c) {
  h2f16 ha = __builtin_bit_cast(h2f16, a), hb = __builtin_bit_cast(h2f16, b);
  return c + (float)ha.x * (float)hb.x + (float)ha.y * (float)hb.y;
}
#endif

__device__ __forceinline__ float redsum64(float a) {
#pragma unroll
  for (int m = 1; m < 64; m <<= 1) a += __shfl_xor(a, m, 64);
  return a;
}

// 512 threads (8 waves), ONE batch element at a time, 2 blocks/CU.
// Thread roles: d = t>>2 (output row / proj row / score row / e), role = t&3.
__global__ __launch_bounds__(512, 4) void decoder_kernel(
    const float* __restrict__ Xg,    // [B,127,128]
    const float* __restrict__ yh,    // [B,127]
    const float* __restrict__ vdw,   // [128]
    const float* __restrict__ vdb,   // [1]
    const float* __restrict__ Wdhs,  // [128,256]
    const float* __restrict__ Wdhsb, // [128]
    const float* __restrict__ Udw,   // [128,128]
    const float* __restrict__ Udb,   // [128]
    const float* __restrict__ ww,    // [129]
    const float* __restrict__ wb,    // [1]
    const float* __restrict__ Wih,   // [512]
    const float* __restrict__ Whh,   // [512,128]
    const float* __restrict__ bih,   // [512]
    const float* __restrict__ bhh,   // [512]
    const float* __restrict__ fcww,  // [256]
    const float* __restrict__ fcb,   // [1]
    float* __restrict__ out)         // [B]
{
  extern __shared__ char smem[];
  unsigned int* u2u = (unsigned int*)smem;       // [127][64] f16-pairs, K2-prescaled U; chunk c at (c ^ (t&15))
  unsigned int* hc2 = u2u + 127 * 64;            // [128]: h-pairs[0..64), c-pairs[64..128)
  float* p2   = (float*)(hc2 + 128);  // [128] K2*(proj + b)
  float* sc   = p2   + 128;           // [128] raw scores (rows 0..126)
  float* XW   = sc   + 128;           // [128] ww @ X[t,:]
  float* yc   = XW   + 128;           // [128] ww[128]*y[s] + wb
  float* beta = yc   + 128;           // [128] softmax (last step only)
  float* hl   = beta + 128;           // [128] final h fp32
  float* ctxl = hl   + 128;           // [128] final ctx
  float* wdbl = ctxl + 128;           // [128] W_dhs_b
  float* v2l  = wdbl + 128;           // [128] -2*v_d
  float* udbl = v2l  + 128;           // [128] U_d bias
  float* fcw  = udbl + 128;           // [256]
  float* wwl  = fcw  + 256;           // [130] w_w(129) + w_b

  const int t    = threadIdx.x;       // 0..511
  const int d    = t >> 2;            // 0..127
  const int role = t & 3;             // i,f,g,o / proj-quarter / e-quarter
  const int g    = role * 128 + d;    // gate row (i[0:128) f[..) g[..) o[..))

  // ---- persistent per-thread weights, f16 pairs (~101 regs incl. scalars) ----
  unsigned int whh2[64];
#pragma unroll
  for (int p = 0; p < 64; ++p)
    whh2[p] = packf16(Whh[g * 128 + 2 * p], Whh[g * 128 + 2 * p + 1]);
  unsigned int wdq[32];               // proj row d, k in [role*64, role*64+64) of concat(h,c)
#pragma unroll
  for (int j = 0; j < 32; ++j)
    wdq[j] = packf16(Wdhs[d * 256 + role * 64 + 2 * j],
                     Wdhs[d * 256 + role * 64 + 2 * j + 1]);
  float bihh = bih[g] + bhh[g];
  float wihr = Wih[g];
  // branch-free nonlinearity constants: role==2 -> tanh, else sigmoid
  float a_c = (role == 2) ? -2.0f : 1.0f;
  float b_c = (role == 2) ? kK2 : -kLog2e;
  float c_c = (role == 2) ? 1.0f : 0.0f;
#pragma unroll
  for (int p = 0; p < 64; ++p) asm volatile("" : "+v"(whh2[p]));
#pragma unroll
  for (int j = 0; j < 32; ++j) asm volatile("" : "+v"(wdq[j]));
  asm volatile("" : "+v"(bihh));
  asm volatile("" : "+v"(wihr));

  // ---- one-time constants to LDS ----
  if (t < 130) wwl[t] = (t < 129) ? ww[t] : wb[0];
  if (t < 256) fcw[t] = fcww[t];
  if (t < 128) { wdbl[t] = Wdhsb[t]; v2l[t] = -2.0f * vdw[t]; udbl[t] = Udb[t]; }
  (void)vdb;  // constant shift, cancels in softmax

  for (int bi = 0; bi < kBPW; ++bi) {
    const int b = blockIdx.x * kBPW + bi;
    const float* Xb = Xg + (size_t)b * (kT * kE);
    float creg = 0.0f;
    __syncthreads();   // previous batch done with LDS

    // ---- staging: zero state, yc, XW, U2 ----
    if (t < 128) hc2[t] = 0u;
    if (t < kT)  yc[t] = wwl[128] * yh[(size_t)b * kT + t] + wwl[129];
    if (d < kT) {
      // XW[d] = ww[0:128] . X[d,:]
      {
        const float* Xq = Xb + d * kE + role * 32;
        const float* wq = wwl + role * 32;
        float a = 0.0f;
#pragma unroll
        for (int q = 0; q < 8; ++q) {
          const float4 xv = *(const float4*)&Xq[q * 4];
          const float4 wv = *(const float4*)&wq[q * 4];
          a += xv.x * wv.x + xv.y * wv.y + xv.z * wv.z + xv.w * wv.w;
        }
        a += __shfl_xor(a, 1, 64);
        a += __shfl_xor(a, 2, 64);
        if (role == 0) XW[d] = a;
      }
      // U2[d, role*32 .. +32) = K2*(X[d,:] @ Udw^T + Udb), f16 pairs, swizzled
      const float* Xrow = Xb + d * kE;
      const int sw = d & 15;
      for (int jh = 0; jh < 4; ++jh) {
        const int eb = role * 32 + jh * 8;
        float acc[8];
#pragma unroll
        for (int j = 0; j < 8; ++j) acc[j] = 0.0f;
        for (int k0 = 0; k0 < kE; k0 += 4) {
          const float4 xq = *(const float4*)&Xrow[k0];
#pragma unroll
          for (int j = 0; j < 8; ++j) {
            const float4 wq = *(const float4*)&Udw[(size_t)(eb + j) * kE + k0];
            acc[j] += xq.x * wq.x + xq.y * wq.y + xq.z * wq.z + xq.w * wq.w;
          }
        }
        const int c = role * 4 + jh;       // 8-elem chunk index, 0..15
        uint4 st;
        st.x = packf16(kK2 * (acc[0] + udbl[eb + 0]), kK2 * (acc[1] + udbl[eb + 1]));
        st.y = packf16(kK2 * (acc[2] + udbl[eb + 2]), kK2 * (acc[3] + udbl[eb + 3]));
        st.z = packf16(kK2 * (acc[4] + udbl[eb + 4]), kK2 * (acc[5] + udbl[eb + 5]));
        st.w = packf16(kK2 * (acc[6] + udbl[eb + 6]), kK2 * (acc[7] + udbl[eb + 7]));
        *(uint4*)&u2u[d * 64 + ((c ^ sw) << 2)] = st;
      }
    }
    __syncthreads();

    // ================= 127 recurrent steps, 3 barriers each =================
    for (int s = 0; s < kT; ++s) {
      // P1: gate row g (in-reg) + proj quarter; h/c via LDS broadcast reads
      float gacc = 0.0f;
#pragma unroll
      for (int m = 0; m < 16; ++m) {
        const uint4 h4 = *(const uint4*)&hc2[m * 4];
        gacc = fdot2f(whh2[m * 4 + 0], h4.x, gacc);
        gacc = fdot2f(whh2[m * 4 + 1], h4.y, gacc);
        gacc = fdot2f(whh2[m * 4 + 2], h4.z, gacc);
        gacc = fdot2f(whh2[m * 4 + 3], h4.w, gacc);
      }
      float pacc = 0.0f;
#pragma unroll
      for (int m = 0; m < 8; ++m) {
        const uint4 q4 = *(const uint4*)&hc2[role * 32 + m * 4];
        pacc = fdot2f(wdq[m * 4 + 0], q4.x, pacc);
        pacc = fdot2f(wdq[m * 4 + 1], q4.y, pacc);
        pacc = fdot2f(wdq[m * 4 + 2], q4.z, pacc);
        pacc = fdot2f(wdq[m * 4 + 3], q4.w, pacc);
      }
      pacc += __shfl_xor(pacc, 1, 64);
      pacc += __shfl_xor(pacc, 2, 64);
      if (role == 0) p2[d] = kK2 * (pacc + wdbl[d]);
      __syncthreads();  // B1

      // P2: score row d over e-quarter [role*32, +32); shift-invariant form
      if (d < kT) {
        const int sw = d & 15;
        float sacc = 0.0f;
#pragma unroll
        for (int i = 0; i < 4; ++i) {
          const int c = role * 4 + i;
          const uint4 uq = *(const uint4*)&u2u[d * 64 + ((c ^ sw) << 2)];
          const int e0 = c * 8;
          const float4 pa = *(const float4*)&p2[e0];
          const float4 va = *(const float4*)&v2l[e0];
          sacc += va.x * RCPF(1.0f + EXP2F(lo16f(uq.x) + pa.x));
          sacc += va.y * RCPF(1.0f + EXP2F(hi16f(uq.x) + pa.y));
          sacc += va.z * RCPF(1.0f + EXP2F(lo16f(uq.y) + pa.z));
          sacc += va.w * RCPF(1.0f + EXP2F(hi16f(uq.y) + pa.w));
          const float4 pb = *(const float4*)&p2[e0 + 4];
          const float4 vb = *(const float4*)&v2l[e0 + 4];
          sacc += vb.x * RCPF(1.0f + EXP2F(lo16f(uq.z) + pb.x));
          sacc += vb.y * RCPF(1.0f + EXP2F(hi16f(uq.z) + pb.y));
          sacc += vb.z * RCPF(1.0f + EXP2F(lo16f(uq.w) + pb.z));
          sacc += vb.w * RCPF(1.0f + EXP2F(hi16f(uq.w) + pb.w));
        }
        sacc += __shfl_xor(sacc, 1, 64);
        sacc += __shfl_xor(sacc, 2, 64);
        if (role == 0) sc[d] = sacc;
      }
      __syncthreads();  // B2

      // P3: softmax + y_tilde, computed redundantly by EVERY wave (no extra barrier)
      const int l = t & 63;
      float num, den;
      {
        const float e0 = EXP2F(sc[l] * kLog2e);
        float e1 = 0.0f, x1 = 0.0f;
        if (l < 63) { e1 = EXP2F(sc[l + 64] * kLog2e); x1 = XW[l + 64]; }
        num = e0 * XW[l] + e1 * x1;
        den = e0 + e1;
#pragma unroll
        for (int m = 1; m < 64; m <<= 1) {
          num += __shfl_xor(num, m, 64);
          den += __shfl_xor(den, m, 64);
        }
      }
      const float rden = RCPF(den);
      const float y_t = num * rden + yc[s];
      if (s == kT - 1 && t < 64) {       // materialize beta only on last step
        beta[l] = EXP2F(sc[l] * kLog2e) * rden;
        beta[l + 64] = (l < 63) ? EXP2F(sc[l + 64] * kLog2e) * rden : 0.0f;
      }

      // P4: gate nonlinearity (branch-free) + in-quad LSTM state update
      const float gate = gacc + bihh + y_t * wihr;
      const float av = c_c + a_c * RCPF(1.0f + EXP2F(b_c * gate));
      const float gv = __shfl_xor(av, 2, 64);   // lane role0 gets g~
      const float fv = __shfl_xor(av, 1, 64);   // lane role0 gets f
      const float ov = __shfl_xor(av, 3, 64);   // lane role0 gets o
      const float cn = fv * creg + av * gv;     // valid on role==0
      creg = cn;
      const float th = 1.0f - 2.0f * RCPF(1.0f + EXP2F(cn * kK2));
      const float hn = ov * th;
      const float ho = __shfl_xor(hn, 4, 64);   // neighbor quad's h (d^1)
      const float co = __shfl_xor(cn, 4, 64);
      if ((t & 7) == 0) {
        hc2[t >> 3]      = packf16(hn, ho);
        hc2[64 + (t >> 3)] = packf16(cn, co);
      }
      if (s == kT - 1 && role == 0) hl[d] = hn;
      __syncthreads();  // B3
    }  // steps

    // ---- final ctx in fp32 from global X; then fc ----
    {
      float cacc = 0.0f;
      for (int i = 0; i < 32; ++i) {
        const int tt = role * 32 + i;
        if (tt < kT) cacc += beta[tt] * Xb[(size_t)tt * kE + d];
      }
      cacc += __shfl_xor(cacc, 1, 64);
      cacc += __shfl_xor(cacc, 2, 64);
      if (role == 0) ctxl[d] = cacc;
    }
    __syncthreads();
    if (t < 64) {
      float a2 = hl[t] * fcw[t] + hl[t + 64] * fcw[64 + t]
               + ctxl[t] * fcw[128 + t] + ctxl[t + 64] * fcw[192 + t];
      a2 = redsum64(a2);
      if (t == 0) out[b] = a2 + fcb[0];
    }
  }  // batch loop
}
}  // namespace

extern "C" void kernel_launch(void* const* d_in, const int* in_sizes, int n_in,
                              void* d_out, int out_size, void* d_ws, size_t ws_size,
                              hipStream_t stream) {
  (void)in_sizes; (void)n_in; (void)d_ws; (void)ws_size; (void)out_size;
  const float* Xg    = (const float*)d_in[0];
  const float* yh    = (const float*)d_in[1];
  const float* vdw   = (const float*)d_in[2];
  const float* vdb   = (const float*)d_in[3];
  const float* Wdhs  = (const float*)d_in[4];
  const float* Wdhsb = (const float*)d_in[5];
  const float* Udw   = (const float*)d_in[6];
  const float* Udb   = (const float*)d_in[7];
  const float* ww    = (const float*)d_in[8];
  const float* wb    = (const float*)d_in[9];
  const float* Wih   = (const float*)d_in[10];
  const float* Whh   = (const float*)d_in[11];
  const float* bih   = (const float*)d_in[12];
  const float* bhh   = (const float*)d_in[13];
  const float* fcww  = (const float*)d_in[14];
  const float* fcb   = (const float*)d_in[15];
  float* out = (float*)d_out;

  hipFuncSetAttribute((const void*)decoder_kernel,
                      hipFuncAttributeMaxDynamicSharedMemorySize, kSmemBytes);
  decoder_kernel<<<dim3(kNWG), dim3(512), kSmemBytes, stream>>>(
      Xg, yh, vdw, vdb, Wdhs, Wdhsb, Udw, Udb, ww, wb,
      Wih, Whh, bih, bhh, fcww, fcb, out);
}

// Round 7
// 7169.224 us; speedup vs baseline: 3.2768x; 3.2768x over previous
//
#include <hip/hip_runtime.h>
#include <hip/hip_bf16.h>

#if __has_builtin(__builtin_amdgcn_exp2f)
#define EXP2F(x) __builtin_amdgcn_exp2f(x)
#else
#define EXP2F(x) exp2f(x)
#endif
#if __has_builtin(__builtin_amdgcn_rcpf)
#define RCPF(x) __builtin_amdgcn_rcpf(x)
#else
#define RCPF(x) (1.0f/(x))
#endif

typedef _Float16 h2f16 __attribute__((ext_vector_type(2)));

namespace {
constexpr int   kT   = 127;
constexpr int   kE   = 128;
constexpr int   kB   = 4096;
constexpr int   kNWG = 256;
constexpr int   kGRP = 4;                  // batches processed simultaneously
constexpr int   kBPW = kB / kNWG;          // 16 batches per block (4 groups)
constexpr float kLog2e = 1.4426950408889634f;
constexpr float kK2    = 2.8853900817779268f;   // 2*log2(e)
// u2u[4][128][64]u + hc2[4][128]u + 7 f32[512] + 3 f32[128] + fcw[256] + wwl[130]
constexpr int   kSmemBytes = 131072 + 2048 + 7 * 2048 + 3 * 512 + 1024 + 520;

__device__ __forceinline__ unsigned int packf16(float a, float b) {
  h2f16 h = { (_Float16)a, (_Float16)b };
  return __builtin_bit_cast(unsigned int, h);
}
__device__ __forceinline__ float lo16f(unsigned int u) {
  h2f16 h = __builtin_bit_cast(h2f16, u); return (float)h.x;
}
__device__ __forceinline__ float hi16f(unsigned int u) {
  h2f16 h = __builtin_bit_cast(h2f16, u); return (float)h.y;
}

#if __has_builtin(__builtin_amdgcn_fdot2)
__device__ __forceinline__ float fdot2f(unsigned int a, unsigned int b, float c) {
  return __builtin_amdgcn_fdot2(__builtin_bit_cast(h2f16, a),
                                __builtin_bit_cast(h2f16, b), c, false);
}
#else
__device__ __forceinline__ float fdot2f(unsigned int a, unsigned int b, float c) {
  h2f16 ha = __builtin_bit_cast(h2f16, a), hb = __builtin_bit_cast(h2f16, b);
  return c + (float)ha.x * (float)hb.x + (float)ha.y * (float)hb.y;
}
#endif

__device__ __forceinline__ float redsum64(float a) {
#pragma unroll
  for (int m = 1; m < 64; m <<= 1) a += __shfl_xor(a, m, 64);
  return a;
}

// 1024 threads, 16 waves, FOUR batch elements per step group, 3 barriers/step.
// Roles: d8 = tid>>3 (0..127), sub = tid&7; gate = sub>>1, khalf = sub&1.
__global__ __launch_bounds__(1024, 4) void decoder_kernel(
    const float* __restrict__ Xg,    // [B,127,128]
    const float* __restrict__ yh,    // [B,127]
    const float* __restrict__ vdw,   // [128]
    const float* __restrict__ vdb,   // [1]
    const float* __restrict__ Wdhs,  // [128,256]
    const float* __restrict__ Wdhsb, // [128]
    const float* __restrict__ Udw,   // [128,128]
    const float* __restrict__ Udb,   // [128]
    const float* __restrict__ ww,    // [129]
    const float* __restrict__ wb,    // [1]
    const float* __restrict__ Wih,   // [512]
    const float* __restrict__ Whh,   // [512,128]
    const float* __restrict__ bih,   // [512]
    const float* __restrict__ bhh,   // [512]
    const float* __restrict__ fcww,  // [256]
    const float* __restrict__ fcb,   // [1]
    float* __restrict__ out)         // [B]
{
  extern __shared__ char smem[];
  unsigned int* u2u  = (unsigned int*)smem;   // [4][128][64]: K2*U as f16 pairs; chunk c at c^(t&15)
  unsigned int* udw2 = u2u + 3 * 8192;        // staging scratch overlay on slot j=3
  unsigned int* hc2  = u2u + 4 * 8192;        // [4][128]: h-pairs[0..64), c-pairs[64..128)
  float* p2   = (float*)(hc2 + 512);  // [4][128] K2*(proj+b)
  float* sc   = p2   + 512;           // [4][128] raw scores
  float* XW   = sc   + 512;           // [4][128] ww . X[t,:]
  float* yc   = XW   + 512;           // [4][128] ww[128]*y + wb
  float* beta = yc   + 512;           // [4][128] softmax (last step only)
  float* hl   = beta + 512;           // [4][128] final h
  float* ctxl = hl   + 512;           // [4][128] final ctx
  float* wdbl = ctxl + 512;           // [128]
  float* v2l  = wdbl + 128;           // [128] -2*v_d
  float* udbl = v2l  + 128;           // [128]
  float* fcw  = udbl + 128;           // [256]
  float* wwl  = fcw  + 256;           // [130]

  const int tid   = threadIdx.x;
  const int d8    = tid >> 3;         // 0..127
  const int sub   = tid & 7;
  const int gate  = sub >> 1;         // 0:i 1:f 2:g 3:o
  const int khalf = sub & 1;
  const int g     = gate * 128 + d8;
  const int lane  = tid & 63;

  // ---- pinned per-thread weights: 48 f16-pairs + 5 scalars (r5-proven budget) ----
  unsigned int whh2[32];              // gate row g, k in [khalf*64, +64)
#pragma unroll
  for (int p = 0; p < 32; ++p)
    whh2[p] = packf16(Whh[g * 128 + khalf * 64 + 2 * p],
                      Whh[g * 128 + khalf * 64 + 2 * p + 1]);
  unsigned int wdq[16];               // proj row d8, k in [sub*32, +32)
#pragma unroll
  for (int q = 0; q < 16; ++q)
    wdq[q] = packf16(Wdhs[d8 * 256 + sub * 32 + 2 * q],
                     Wdhs[d8 * 256 + sub * 32 + 2 * q + 1]);
  float bihh = bih[g] + bhh[g];
  float wihr = Wih[g];
  const float a_c = (gate == 2) ? -2.0f : 1.0f;
  const float b_c = (gate == 2) ? kK2 : -kLog2e;
  const float c_c = (gate == 2) ? 1.0f : 0.0f;
#pragma unroll
  for (int p = 0; p < 32; ++p) asm volatile("" : "+v"(whh2[p]));
#pragma unroll
  for (int q = 0; q < 16; ++q) asm volatile("" : "+v"(wdq[q]));
  asm volatile("" : "+v"(bihh));
  asm volatile("" : "+v"(wihr));

  // ---- one-time constants ----
  if (tid < 130) wwl[tid] = (tid < 129) ? ww[tid] : wb[0];
  if (tid < 256) fcw[tid] = fcww[tid];
  if (tid < 128) { wdbl[tid] = Wdhsb[tid]; v2l[tid] = -2.0f * vdw[tid]; udbl[tid] = Udb[tid]; }
  (void)vdb;   // cancels in softmax

  for (int grp = 0; grp < kBPW / kGRP; ++grp) {
    const int b0 = blockIdx.x * kBPW + grp * kGRP;
    float creg[kGRP] = {0.f, 0.f, 0.f, 0.f};
    __syncthreads();   // previous group done with LDS

    // ---- S1: stage Udw f16 (swizzled for broadcast) + init state/yc/XW pad ----
    {
      const int r = tid >> 3, mb = (tid & 7) * 2;
#pragma unroll
      for (int ch = 0; ch < 2; ++ch) {
        const int m = mb + ch;
        const float4 wa = *(const float4*)&Udw[r * kE + m * 8];
        const float4 wb4 = *(const float4*)&Udw[r * kE + m * 8 + 4];
        uint4 st;
        st.x = packf16(wa.x, wa.y);  st.y = packf16(wa.z, wa.w);
        st.z = packf16(wb4.x, wb4.y); st.w = packf16(wb4.z, wb4.w);
        *(uint4*)&udw2[r * 64 + ((m ^ (r >> 4)) << 2)] = st;
      }
    }
    if (tid < 512) {
      const int j = tid >> 7, s2 = tid & 127;
      hc2[tid] = 0u;
      yc[tid] = (s2 < kT) ? wwl[128] * yh[(size_t)(b0 + j) * kT + s2] + wwl[129] : 0.f;
      if (s2 == 127) XW[tid] = 0.f;
    }
    __syncthreads();

    // ---- S2: U2 = K2*(X @ Udw^T + Udb) (f16, swizzled) + XW, 4 batches ----
    uint4 st3a, st3b;
    if (d8 < kT) {
#pragma unroll
      for (int j = 0; j < kGRP; ++j) {
        const float* Xrow = Xg + (size_t)(b0 + j) * (kT * kE) + d8 * kE;
        // XW[j][d8]
        float a = 0.f;
#pragma unroll
        for (int q = 0; q < 4; ++q) {
          const float4 xv = *(const float4*)&Xrow[sub * 16 + q * 4];
          const float4 wv = *(const float4*)&wwl[sub * 16 + q * 4];
          a += xv.x * wv.x + xv.y * wv.y + xv.z * wv.z + xv.w * wv.w;
        }
        a += __shfl_xor(a, 1, 64);
        a += __shfl_xor(a, 2, 64);
        a += __shfl_xor(a, 4, 64);
        if (sub == 0) XW[j * 128 + d8] = a;
        // U2 outputs e in [sub*16, +16)
        float acc[16];
#pragma unroll
        for (int jj = 0; jj < 16; ++jj) acc[jj] = 0.f;
        for (int m = 0; m < 16; ++m) {
          const float4 xa = *(const float4*)&Xrow[m * 8];
          const float4 xb4 = *(const float4*)&Xrow[m * 8 + 4];
          const unsigned int xp0 = packf16(xa.x, xa.y), xp1 = packf16(xa.z, xa.w);
          const unsigned int xp2 = packf16(xb4.x, xb4.y), xp3 = packf16(xb4.z, xb4.w);
#pragma unroll
          for (int jj = 0; jj < 16; ++jj) {
            const uint4 wq = *(const uint4*)&udw2[(sub * 16 + jj) * 64 + ((m ^ sub) << 2)];
            acc[jj] = fdot2f(xp3, wq.w, fdot2f(xp2, wq.z,
                      fdot2f(xp1, wq.y, fdot2f(xp0, wq.x, acc[jj]))));
          }
        }
        uint4 s0, s1;
        const int eb = sub * 16;
        s0.x = packf16(kK2 * (acc[0] + udbl[eb + 0]), kK2 * (acc[1] + udbl[eb + 1]));
        s0.y = packf16(kK2 * (acc[2] + udbl[eb + 2]), kK2 * (acc[3] + udbl[eb + 3]));
        s0.z = packf16(kK2 * (acc[4] + udbl[eb + 4]), kK2 * (acc[5] + udbl[eb + 5]));
        s0.w = packf16(kK2 * (acc[6] + udbl[eb + 6]), kK2 * (acc[7] + udbl[eb + 7]));
        s1.x = packf16(kK2 * (acc[8] + udbl[eb + 8]), kK2 * (acc[9] + udbl[eb + 9]));
        s1.y = packf16(kK2 * (acc[10] + udbl[eb + 10]), kK2 * (acc[11] + udbl[eb + 11]));
        s1.z = packf16(kK2 * (acc[12] + udbl[eb + 12]), kK2 * (acc[13] + udbl[eb + 13]));
        s1.w = packf16(kK2 * (acc[14] + udbl[eb + 14]), kK2 * (acc[15] + udbl[eb + 15]));
        if (j < 3) {
          *(uint4*)&u2u[j * 8192 + d8 * 64 + (((sub * 2 + 0) ^ (d8 & 15)) << 2)] = s0;
          *(uint4*)&u2u[j * 8192 + d8 * 64 + (((sub * 2 + 1) ^ (d8 & 15)) << 2)] = s1;
        } else { st3a = s0; st3b = s1; }
      }
    }
    __syncthreads();   // udw2 fully consumed
    if (d8 < kT) {
      *(uint4*)&u2u[3 * 8192 + d8 * 64 + (((sub * 2 + 0) ^ (d8 & 15)) << 2)] = st3a;
      *(uint4*)&u2u[3 * 8192 + d8 * 64 + (((sub * 2 + 1) ^ (d8 & 15)) << 2)] = st3b;
    }
    // (j=3 stores separated from first read by B1 inside the step loop)

    // ================= 127 steps × 4 batches, 3 barriers each =================
    for (int s = 0; s < kT; ++s) {
      // P1: gate dot (full row via khalf+shfl) + proj (8-way sub shfl-reduce), 4 batches
      float gc[kGRP];
#pragma unroll
      for (int j = 0; j < kGRP; ++j) {
        float ga = 0.f;
        const unsigned int* hb = &hc2[j * 128 + khalf * 32];
#pragma unroll
        for (int q = 0; q < 8; ++q) {
          const uint4 h4 = *(const uint4*)&hb[q * 4];
          ga = fdot2f(whh2[q * 4 + 0], h4.x, ga);
          ga = fdot2f(whh2[q * 4 + 1], h4.y, ga);
          ga = fdot2f(whh2[q * 4 + 2], h4.z, ga);
          ga = fdot2f(whh2[q * 4 + 3], h4.w, ga);
        }
        gc[j] = ga + __shfl_xor(ga, 1, 64);
        float pa = 0.f;
        const unsigned int* pb = &hc2[j * 128 + sub * 16];
#pragma unroll
        for (int q = 0; q < 4; ++q) {
          const uint4 h4 = *(const uint4*)&pb[q * 4];
          pa = fdot2f(wdq[q * 4 + 0], h4.x, pa);
          pa = fdot2f(wdq[q * 4 + 1], h4.y, pa);
          pa = fdot2f(wdq[q * 4 + 2], h4.z, pa);
          pa = fdot2f(wdq[q * 4 + 3], h4.w, pa);
        }
        pa += __shfl_xor(pa, 1, 64);
        pa += __shfl_xor(pa, 2, 64);
        pa += __shfl_xor(pa, 4, 64);
        if (sub == 0) p2[j * 128 + d8] = kK2 * (pa + wdbl[d8]);
      }
      __syncthreads();  // B1

      // P3: scores — 2 lanes per (j,t) row, 64 e each
      {
        const int rr = tid >> 1, tt = rr & 127, half = tid & 1;
        if (tt < kT) {
          const int jj3 = rr >> 7, sw = tt & 15;
          const unsigned int* urow = u2u + jj3 * 8192 + tt * 64;
          const float* p2j = p2 + jj3 * 128;
          float sacc = 0.f;
#pragma unroll
          for (int i = 0; i < 8; ++i) {
            const int c = half * 8 + i;
            const uint4 uq = *(const uint4*)(urow + ((c ^ sw) << 2));
            const int e0 = c * 8;
            const float4 pa = *(const float4*)(p2j + e0);
            const float4 va = *(const float4*)(v2l + e0);
            sacc += va.x * RCPF(1.f + EXP2F(lo16f(uq.x) + pa.x));
            sacc += va.y * RCPF(1.f + EXP2F(hi16f(uq.x) + pa.y));
            sacc += va.z * RCPF(1.f + EXP2F(lo16f(uq.y) + pa.z));
            sacc += va.w * RCPF(1.f + EXP2F(hi16f(uq.y) + pa.w));
            const float4 pbv = *(const float4*)(p2j + e0 + 4);
            const float4 vb = *(const float4*)(v2l + e0 + 4);
            sacc += vb.x * RCPF(1.f + EXP2F(lo16f(uq.z) + pbv.x));
            sacc += vb.y * RCPF(1.f + EXP2F(hi16f(uq.z) + pbv.y));
            sacc += vb.z * RCPF(1.f + EXP2F(lo16f(uq.w) + pbv.z));
            sacc += vb.w * RCPF(1.f + EXP2F(hi16f(uq.w) + pbv.w));
          }
          sacc += __shfl_xor(sacc, 1, 64);
          if (half == 0) sc[rr] = sacc;
        }
      }
      __syncthreads();  // B2

      // P4: redundant per-wave softmax+y_tilde -> in-reg gates -> in-group LSTM
      float rden[kGRP];
      {
        float y_t[kGRP];
#pragma unroll
        for (int j = 0; j < kGRP; ++j) {
          const float e0v = EXP2F(sc[j * 128 + lane] * kLog2e);
          float e1v = 0.f, x1 = 0.f;
          if (lane < 63) {
            e1v = EXP2F(sc[j * 128 + 64 + lane] * kLog2e);
            x1 = XW[j * 128 + 64 + lane];
          }
          float num = e0v * XW[j * 128 + lane] + e1v * x1;
          float den = e0v + e1v;
#pragma unroll
          for (int m = 1; m < 64; m <<= 1) {
            num += __shfl_xor(num, m, 64);
            den += __shfl_xor(den, m, 64);
          }
          rden[j] = RCPF(den);
          y_t[j] = num * rden[j] + yc[j * 128 + s];
        }
#pragma unroll
        for (int j = 0; j < kGRP; ++j) {
          const float av = c_c + a_c * RCPF(1.f + EXP2F(b_c * (gc[j] + bihh + y_t[j] * wihr)));
          const float fv = __shfl_xor(av, 2, 64);
          const float gv = __shfl_xor(av, 4, 64);
          const float ov = __shfl_xor(av, 6, 64);
          const float cn = fv * creg[j] + av * gv;      // valid on sub==0
          creg[j] = cn;
          const float th = 1.f - 2.f * RCPF(1.f + EXP2F(cn * kK2));
          const float hn = ov * th;
          const float ho = __shfl_xor(hn, 8, 64);
          const float co = __shfl_xor(cn, 8, 64);
          if ((tid & 15) == 0) {
            hc2[j * 128 + (d8 >> 1)]      = packf16(hn, ho);
            hc2[j * 128 + 64 + (d8 >> 1)] = packf16(cn, co);
          }
          if (s == kT - 1 && sub == 0) hl[j * 128 + d8] = hn;
        }
      }
      if (s == kT - 1 && tid < 512) {
        const int j = tid >> 7, t2 = tid & 127;
        beta[tid] = (t2 < kT) ? EXP2F(sc[tid] * kLog2e) * rden[j] : 0.f;
      }
      __syncthreads();  // B3
    }  // steps

    // ---- final ctx in fp32 from global X; then fc (4 outputs) ----
    {
      const int j = tid >> 8, r = tid & 255, e = r >> 1, hf = r & 1;
      const float* Xbj = Xg + (size_t)(b0 + j) * (kT * kE);
      float cacc = 0.f;
#pragma unroll
      for (int i = 0; i < 64; ++i) {
        const int t2 = hf * 64 + i;
        if (t2 < kT) cacc += beta[j * 128 + t2] * Xbj[(size_t)t2 * kE + e];
      }
      cacc += __shfl_xor(cacc, 1, 64);
      if (hf == 0) ctxl[j * 128 + e] = cacc;
    }
    __syncthreads();
    if (tid < 256) {
      const int j = tid >> 6, l = tid & 63;
      float a2 = hl[j * 128 + l] * fcw[l] + hl[j * 128 + 64 + l] * fcw[64 + l]
               + ctxl[j * 128 + l] * fcw[128 + l] + ctxl[j * 128 + 64 + l] * fcw[192 + l];
      a2 = redsum64(a2);
      if (l == 0) out[b0 + j] = a2 + fcb[0];
    }
  }  // group loop
}
}  // namespace

extern "C" void kernel_launch(void* const* d_in, const int* in_sizes, int n_in,
                              void* d_out, int out_size, void* d_ws, size_t ws_size,
                              hipStream_t stream) {
  (void)in_sizes; (void)n_in; (void)d_ws; (void)ws_size; (void)out_size;
  const float* Xg    = (const float*)d_in[0];
  const float* yh    = (const float*)d_in[1];
  const float* vdw   = (const float*)d_in[2];
  const float* vdb   = (const float*)d_in[3];
  const float* Wdhs  = (const float*)d_in[4];
  const float* Wdhsb = (const float*)d_in[5];
  const float* Udw   = (const float*)d_in[6];
  const float* Udb   = (const float*)d_in[7];
  const float* ww    = (const float*)d_in[8];
  const float* wb    = (const float*)d_in[9];
  const float* Wih   = (const float*)d_in[10];
  const float* Whh   = (const float*)d_in[11];
  const float* bih   = (const float*)d_in[12];
  const float* bhh   = (const float*)d_in[13];
  const float* fcww  = (const float*)d_in[14];
  const float* fcb   = (const float*)d_in[15];
  float* out = (float*)d_out;

  hipFuncSetAttribute((const void*)decoder_kernel,
                      hipFuncAttributeMaxDynamicSharedMemorySize, kSmemBytes);
  decoder_kernel<<<dim3(kNWG), dim3(1024), kSmemBytes, stream>>>(
      Xg, yh, vdw, vdb, Wdhs, Wdhsb, Udw, Udb, ww, wb,
      Wih, Whh, bih, bhh, fcww, fcb, out);
}